// Round 19
// baseline (1311.164 us; speedup 1.0000x reference)
//
#include <hip/hip_runtime.h>

#define N_NODE 50000
#define N_EDGE 400000
#define INF    128

#define FUSED_BLOCKS 1536   // 6 blocks/CU x 4 waves; 8 nodes per block-pass

// 32-row tiles within type segments (boundaries 10000/20000 are 16-aligned)
#define TILES0 313
#define TILES1 313
#define TILES2 938
#define PTILES 1564
#define PBLOCKS2 782        // 2 tiles/block, 2 waves per tile (ct-split)

// k_setup grid partition
#define SB_CONCAT 2048
#define SB_COUNT  1563
#define SB_TWT    768
#define SB_TRMSG  32
#define SB_TOTAL  (SB_CONCAT + SB_COUNT + SB_TWT + SB_TRMSG)

typedef __bf16 bf16x8 __attribute__((ext_vector_type(8)));
typedef float  f32x4  __attribute__((ext_vector_type(4)));

__device__ __forceinline__ void seg_decode(int b, int& ty, int& base, int& nrows) {
  if (b < TILES0)            { ty = 0; base = b * 32;                      nrows = 10000 - base; }
  else if (b < TILES0+TILES1){ ty = 1; base = 10000 + (b - TILES0) * 32;   nrows = 20000 - base; }
  else                       { ty = 2; base = 20000 + (b - TILES0-TILES1)*32; nrows = 50000 - base; }
  if (nrows > 32) nrows = 32;
}

__device__ __forceinline__ float blo(unsigned u) { return __uint_as_float(u << 16); }
__device__ __forceinline__ float bhi(unsigned u) { return __uint_as_float(u & 0xffff0000u); }
// pack two f32 -> bf16x2 (RNE), lo = even dim, hi = odd dim
__device__ __forceinline__ unsigned bpack(float lo, float hi) {
  unsigned a = __float_as_uint(lo), b = __float_as_uint(hi);
  a = (a + 0x7fffu + ((a >> 16) & 1u)) >> 16;
  b = (b + 0x7fffu + ((b >> 16) & 1u)) & 0xffff0000u;
  return a | b;
}
__device__ __forceinline__ unsigned short b16(float v) {
  unsigned u = __float_as_uint(v);
  return (unsigned short)((u + 0x7fffu + ((u >> 16) & 1u)) >> 16);
}
__device__ __forceinline__ bf16x8 ld_frag(const unsigned short* p) {
  uint4 u = *reinterpret_cast<const uint4*>(p);
  return __builtin_bit_cast(bf16x8, u);
}

// ---- merged setup: concat(x,xh) | deg count | WT transpose | AmT ---------
__global__ __launch_bounds__(256) void k_setup(const float* __restrict__ dr,
                                               const float* __restrict__ di,
                                               const float* __restrict__ pr,
                                               float* __restrict__ x,
                                               unsigned short* __restrict__ xh,
                                               const int* __restrict__ dst,
                                               int* __restrict__ deg,
                                               const float* __restrict__ Wk,
                                               const float* __restrict__ Wq,
                                               const float* __restrict__ Wv,
                                               const float* __restrict__ Wa,
                                               unsigned short* __restrict__ WT,
                                               const float* __restrict__ rm,
                                               float* __restrict__ AmT) {
  int b = blockIdx.x;
  if (b < SB_CONCAT) {
    for (int i = b * 256 + threadIdx.x; i < N_NODE * 32; i += SB_CONCAT * 256) {
      int row = i >> 5;
      float4 val;
      if (row < 10000)      val = ((const float4*)dr)[i];
      else if (row < 20000) val = ((const float4*)di)[i - 10000*32];
      else                  val = ((const float4*)pr)[i - 20000*32];
      ((float4*)x)[i] = val;
      ((uint2*)xh)[i] = make_uint2(bpack(val.x, val.y), bpack(val.z, val.w));
    }
  } else if (b < SB_CONCAT + SB_COUNT) {
    int e = (b - SB_CONCAT) * 256 + threadIdx.x;
    if (e < N_EDGE) atomicAdd(&deg[dst[e]], 1);
  } else if (b < SB_CONCAT + SB_COUNT + SB_TWT) {
    int idx = (b - SB_CONCAT - SB_COUNT) * 256 + threadIdx.x;
    if (idx < 196608) {
      int mt = idx >> 14;            // mat*3+ty
      int within = idx & 16383;
      int o = within >> 7, ii = within & 127;
      int mat = mt / 3, ty = mt % 3;
      const float* W = (mat == 0) ? Wk : (mat == 1) ? Wq : (mat == 2) ? Wv : Wa;
      WT[idx] = b16(W[ty * 16384 + ii * 128 + o]);
    }
  } else {
    int i = (b - SB_CONCAT - SB_COUNT - SB_TWT) * 256 + threadIdx.x;  // < 8192
    int di2 = i & 15, doo = (i >> 4) & 15, ty = (i >> 8) & 3, hh = i >> 10;
    AmT[i] = rm[((hh * 4 + ty) * 16 + di2) * 16 + doo];
  }
}

// ---- CSR scan ------------------------------------------------------------
__global__ __launch_bounds__(1024) void k_scan(const int* __restrict__ deg,
                                               int* __restrict__ off, int* __restrict__ cur) {
  __shared__ int part[1024];
  int t = threadIdx.x;
  int c0 = t * 49;
  int c1 = c0 + 49; if (c1 > N_NODE) c1 = N_NODE;
  int s = 0;
  for (int i = c0; i < c1; ++i) s += deg[i];
  part[t] = s;
  __syncthreads();
  for (int ofs = 1; ofs < 1024; ofs <<= 1) {
    int v = (t >= ofs) ? part[t - ofs] : 0;
    __syncthreads();
    part[t] += v;
    __syncthreads();
  }
  int run = (t == 0) ? 0 : part[t - 1];
  for (int i = c0; i < c1; ++i) { off[i] = run; cur[i] = run; run += deg[i]; }
  if (t == 1023) off[N_NODE] = part[1023];
}

// writes combined edge record est[p] = (src<<2) | etype; pads est tail with 0
__global__ __launch_bounds__(256) void k_fill(const int* __restrict__ dst,
                                              const int* __restrict__ src,
                                              const int* __restrict__ etp,
                                              int* __restrict__ cur, int* __restrict__ est) {
  int e = blockIdx.x * 256 + threadIdx.x;
  if (e < N_EDGE) {
    int p = atomicAdd(&cur[dst[e]], 1);
    est[p] = (src[e] << 2) | etp[e];
  } else if (e < N_EDGE + 128) {
    est[e] = 0;
  }
}

// ---- typed K/Q/V projection via MFMA + fused qa precompute ---------------
// 2 waves per 32-row tile; wave owns 4 of 8 ct-columns.
__global__ __launch_bounds__(256) void k_qkv(const unsigned short* __restrict__ xh,
                                             const unsigned short* __restrict__ WT,
                                             const float* __restrict__ rel_att,
                                             const float* __restrict__ pri,
                                             uint2* __restrict__ kvb,
                                             uint4* __restrict__ qab) {
  __shared__ unsigned short qsh[2][32][136];   // bf16 q rows per tile, 17.4 KB
  int w = threadIdx.x >> 6, l = threadIdx.x & 63;
  int r16 = l & 15, ks = l >> 4;
  int t = w >> 1, ch = w & 1;
  int tile = blockIdx.x * 2 + t;
  int ty, base, wrows;
  seg_decode(tile, ty, base, wrows);
  int row0 = base;

  bf16x8 a[2][4];
#pragma unroll
  for (int st = 0; st < 2; ++st) {
    const unsigned short* xrow = xh + (size_t)(row0 + st * 16 + r16) * 128 + ks * 8;
#pragma unroll
    for (int kk = 0; kk < 4; ++kk) a[st][kk] = ld_frag(xrow + kk * 32);
  }

  const unsigned short* WK = WT + (size_t)(0 * 3 + ty) * 16384;
  const unsigned short* WQ = WT + (size_t)(1 * 3 + ty) * 16384;
  const unsigned short* WV = WT + (size_t)(2 * 3 + ty) * 16384;

#pragma unroll 1
  for (int ct = ch * 4; ct < ch * 4 + 4; ++ct) {
    int o = ct * 16 + r16;
    bf16x8 fbk[4], fbq[4], fbv[4];
#pragma unroll
    for (int kk = 0; kk < 4; ++kk) {
      fbk[kk] = ld_frag(WK + (size_t)o * 128 + ks * 8 + kk * 32);
      fbq[kk] = ld_frag(WQ + (size_t)o * 128 + ks * 8 + kk * 32);
      fbv[kk] = ld_frag(WV + (size_t)o * 128 + ks * 8 + kk * 32);
    }
#pragma unroll
    for (int st = 0; st < 2; ++st) {
      f32x4 ak = {0.f,0.f,0.f,0.f}, aq = {0.f,0.f,0.f,0.f}, av = {0.f,0.f,0.f,0.f};
#pragma unroll
      for (int kk = 0; kk < 4; ++kk) {
        ak = __builtin_amdgcn_mfma_f32_16x16x32_bf16(a[st][kk], fbk[kk], ak, 0, 0, 0);
        aq = __builtin_amdgcn_mfma_f32_16x16x32_bf16(a[st][kk], fbq[kk], aq, 0, 0, 0);
        av = __builtin_amdgcn_mfma_f32_16x16x32_bf16(a[st][kk], fbv[kk], av, 0, 0, 0);
      }
#pragma unroll
      for (int r = 0; r < 4; ++r) {
        int rrel = st * 16 + ks * 4 + r;       // < 32 always
        float kn = __shfl_xor(ak[r], 1);
        float vn = __shfl_xor(av[r], 1);
        qsh[t][rrel][o] = b16(aq[r]);
        if (rrel < wrows && (l & 1) == 0) {
          size_t p = (size_t)(row0 + rrel);
          kvb[p * 64 + (o >> 1)] = make_uint2(bpack(ak[r], kn), bpack(av[r], vn));
        }
      }
    }
  }
  __syncthreads();

  // ---- qa phase: this wave handles rows [ch*16, ch*16+16) of its tile ----
  int h = l >> 3, j = l & 7;
  float4 prh = ((const float4*)pri)[h];
  float prs[4] = { prh.x * 0.25f, prh.y * 0.25f, prh.z * 0.25f, prh.w * 0.25f };
  int nd0 = ch * 16;
  int lim = wrows - nd0; if (lim > 16) lim = 16;
  for (int i = 0; i < lim; ++i) {
    int nd = nd0 + i;
    unsigned u[8];
    *(uint4*)&u[0] = *(uint4*)&qsh[t][nd][h * 16 + 0];
    *(uint4*)&u[4] = *(uint4*)&qsh[t][nd][h * 16 + 8];
    float qf[16];
#pragma unroll
    for (int q2 = 0; q2 < 8; ++q2) { qf[2*q2] = blo(u[q2]); qf[2*q2+1] = bhi(u[q2]); }
    unsigned pk[4];
#pragma unroll
    for (int t4 = 0; t4 < 4; ++t4) {
      const float* Ar = rel_att + (((h * 4 + t4) * 16) + 2 * j) * 16;
      float ax = 0.f, ay = 0.f;
#pragma unroll
      for (int o = 0; o < 16; ++o) {
        ax += Ar[o] * qf[o];
        ay += Ar[16 + o] * qf[o];
      }
      pk[t4] = bpack(ax * prs[t4], ay * prs[t4]);
    }
    qab[(size_t)(row0 + nd) * 64 + l] = make_uint4(pk[0], pk[1], pk[2], pk[3]);
  }
}

// ---- fused attention: 2 nodes per wave (32 lanes each) -------------------
// lane l: half = l>>5 (node select), m = l&31, dims 4m..4m+3, head = m>>2.
// Per edge: one uint4 gather (16B/lane x 32 = 512B), 2 shfl_xor for the
// head dot (4-lane groups), no-max softmax, 4-ty float4 accumulators.
// Wave-uniform trip counts via degmax = max over both halves.
__global__ __launch_bounds__(256)
__attribute__((amdgpu_waves_per_eu(3, 6)))
void k_fused(const uint2* __restrict__ kvb,
             const uint4* __restrict__ qab,
             const int* __restrict__ off,
             const int* __restrict__ est,
             const float* __restrict__ AmT,
             unsigned* __restrict__ hbh) {
  __shared__ float accs[4][2][4][128];   // [wave][half][ty][dim], 16 KB
  const uint4* kv4 = (const uint4*)kvb;
  int w = threadIdx.x >> 6, l = threadIdx.x & 63;
  int half = l >> 5, m = l & 31;
  int h = m >> 2, q4 = (m & 3) * 4;
  int hbase = l & 32;                    // shfl base of this half

  for (int nb = blockIdx.x * 8 + w * 2; nb < N_NODE; nb += FUSED_BLOCKS * 8) {
    int n = nb + half;                   // N_NODE even -> always valid
    int o0 = off[n], o1 = off[n + 1];
    int deg = o1 - o0;
    int degmax = max(deg, __shfl_xor(deg, 32));

    uint4 qu0 = qab[(size_t)n * 64 + 2 * m];
    uint4 qu1 = qab[(size_t)n * 64 + 2 * m + 1];
    float4 qa0 = make_float4(blo(qu0.x), bhi(qu0.x), blo(qu1.x), bhi(qu1.x));
    float4 qa1 = make_float4(blo(qu0.y), bhi(qu0.y), blo(qu1.y), bhi(qu1.y));
    float4 qa2 = make_float4(blo(qu0.z), bhi(qu0.z), blo(qu1.z), bhi(qu1.z));
    float4 qa3 = make_float4(blo(qu0.w), bhi(qu0.w), blo(qu1.w), bhi(qu1.w));

    float ssum = 0.f;
    float4 z = make_float4(0.f, 0.f, 0.f, 0.f);
    float4 at0 = z, at1 = z, at2 = z, at3 = z;

#define PROC(KV, T, VALID) { \
    int ty = (T) & 3; \
    float k0 = blo((KV).x), k1 = bhi((KV).x), k2 = blo((KV).z), k3 = bhi((KV).z); \
    float4 qat = (ty==0)?qa0:(ty==1)?qa1:(ty==2)?qa2:qa3; \
    float part = k0*qat.x + k1*qat.y + k2*qat.z + k3*qat.w; \
    part += __shfl_xor(part, 1); \
    part += __shfl_xor(part, 2); \
    float wgt = (VALID) ? __expf(part) : 0.f; \
    ssum += wgt; \
    float v0 = blo((KV).y), v1 = bhi((KV).y), v2 = blo((KV).w), v3 = bhi((KV).w); \
    float w0=(ty==0)?wgt:0.f, w1=(ty==1)?wgt:0.f, w2=(ty==2)?wgt:0.f, w3=(ty==3)?wgt:0.f; \
    at0.x += w0*v0; at0.y += w0*v1; at0.z += w0*v2; at0.w += w0*v3; \
    at1.x += w1*v0; at1.y += w1*v1; at1.z += w1*v2; at1.w += w1*v3; \
    at2.x += w2*v0; at2.y += w2*v1; at2.z += w2*v2; at2.w += w2*v3; \
    at3.x += w3*v0; at3.y += w3*v1; at3.z += w3*v2; at3.w += w3*v3; }

    for (int b0 = 0; b0 < degmax; b0 += 32) {
      int cnt = deg - b0; if (cnt > 32) cnt = 32; if (cnt < 0) cnt = 0;
      int cmax = degmax - b0; if (cmax > 32) cmax = 32;
      int cidx = (cnt > 0) ? (m < cnt ? m : cnt - 1) : 0;
      int stv = est[o0 + b0 + cidx];
#define SLOT(I) (((I) < cnt) ? (I) : (cnt > 0 ? cnt - 1 : 0))
      int t0 = __shfl(stv, hbase + SLOT(0));
      int t1 = __shfl(stv, hbase + SLOT(1));
      uint4 kv0 = kv4[(size_t)(t0 >> 2) * 32 + m];
      uint4 kv1 = kv4[(size_t)(t1 >> 2) * 32 + m];
      for (int i = 0; i < cmax; i += 2) {
        bool more = (i + 2) < cmax;       // wave-uniform
        int n0 = 0, n1 = 0; uint4 kn0, kn1;
        if (more) {
          n0 = __shfl(stv, hbase + SLOT(i + 2));
          n1 = __shfl(stv, hbase + SLOT(i + 3));
          kn0 = kv4[(size_t)(n0 >> 2) * 32 + m];
          kn1 = kv4[(size_t)(n1 >> 2) * 32 + m];
        }
        PROC(kv0, t0, i < cnt)
        PROC(kv1, t1, (i + 1) < cnt)
        if (more) { t0 = n0; t1 = n1; kv0 = kn0; kv1 = kn1; }
      }
#undef SLOT
    }
#undef PROC

    float inv = (ssum > 0.f) ? 1.f / ssum : 0.f;
    at0.x *= inv; at0.y *= inv; at0.z *= inv; at0.w *= inv;
    at1.x *= inv; at1.y *= inv; at1.z *= inv; at1.w *= inv;
    at2.x *= inv; at2.y *= inv; at2.z *= inv; at2.w *= inv;
    at3.x *= inv; at3.y *= inv; at3.z *= inv; at3.w *= inv;

    ((float4*)&accs[w][half][0][0])[m] = at0;
    ((float4*)&accs[w][half][1][0])[m] = at1;
    ((float4*)&accs[w][half][2][0])[m] = at2;
    ((float4*)&accs[w][half][3][0])[m] = at3;

    float o0v = 0.f, o1v = 0.f, o2v = 0.f, o3v = 0.f;
#pragma unroll
    for (int ty = 0; ty < 4; ++ty) {
      float4 c0 = *(float4*)&accs[w][half][ty][16 * h + 0];
      float4 c1 = *(float4*)&accs[w][half][ty][16 * h + 4];
      float4 c2 = *(float4*)&accs[w][half][ty][16 * h + 8];
      float4 c3 = *(float4*)&accs[w][half][ty][16 * h + 12];
      const float4* AmR = (const float4*)(AmT + ((size_t)((h * 4 + ty) * 16 + q4)) * 16);
#define ROWDOT(R) (AmR[(R)*4+0].x*c0.x + AmR[(R)*4+0].y*c0.y + AmR[(R)*4+0].z*c0.z + AmR[(R)*4+0].w*c0.w \
                 + AmR[(R)*4+1].x*c1.x + AmR[(R)*4+1].y*c1.y + AmR[(R)*4+1].z*c1.z + AmR[(R)*4+1].w*c1.w \
                 + AmR[(R)*4+2].x*c2.x + AmR[(R)*4+2].y*c2.y + AmR[(R)*4+2].z*c2.z + AmR[(R)*4+2].w*c2.w \
                 + AmR[(R)*4+3].x*c3.x + AmR[(R)*4+3].y*c3.y + AmR[(R)*4+3].z*c3.z + AmR[(R)*4+3].w*c3.w)
      o0v += ROWDOT(0);
      o1v += ROWDOT(1);
      o2v += ROWDOT(2);
      o3v += ROWDOT(3);
#undef ROWDOT
    }
    ((uint2*)hbh)[(size_t)n * 32 + m] = make_uint2(bpack(o0v, o1v), bpack(o2v, o3v));
  }
}

// ---- fused: output proj (layer L) + K/Q/V proj (layer L+1) ---------------
__global__ __launch_bounds__(256) void k_outqkv(const unsigned short* __restrict__ hbh,
                                                const unsigned short* __restrict__ WT,
                                                const float* __restrict__ skipv,
                                                const float* __restrict__ rel_att,
                                                const float* __restrict__ pri,
                                                float* __restrict__ xio,
                                                uint2* __restrict__ kvb,
                                                uint4* __restrict__ qab) {
  __shared__ unsigned short qsh[2][32][136];   // 17.4 KB
  int w = threadIdx.x >> 6, l = threadIdx.x & 63;
  int r16 = l & 15, ks = l >> 4;
  int t = w >> 1, ch = w & 1;
  int tile = blockIdx.x * 2 + t;
  int ty, base, wrows;
  seg_decode(tile, ty, base, wrows);
  int row0 = base;

  // ---- Phase A: output projection + sigmoid-skip residual (4 cts) ----
  {
    bf16x8 a[2][4];
#pragma unroll
    for (int st = 0; st < 2; ++st) {
      const unsigned short* hrow = hbh + (size_t)(row0 + st * 16 + r16) * 128 + ks * 8;
#pragma unroll
      for (int kk = 0; kk < 4; ++kk) a[st][kk] = ld_frag(hrow + kk * 32);
    }
    const unsigned short* WA = WT + (size_t)(3 * 3 + ty) * 16384;
    float alpha = 1.f / (1.f + __expf(-skipv[ty]));
    float beta = 1.f - alpha;
#pragma unroll 1
    for (int ct = ch * 4; ct < ch * 4 + 4; ++ct) {
      int o = ct * 16 + r16;
      bf16x8 ba[4];
#pragma unroll
      for (int kk = 0; kk < 4; ++kk)
        ba[kk] = ld_frag(WA + (size_t)o * 128 + ks * 8 + kk * 32);
#pragma unroll
      for (int st = 0; st < 2; ++st) {
        f32x4 acc = {0.f,0.f,0.f,0.f};
#pragma unroll
        for (int kk = 0; kk < 4; ++kk)
          acc = __builtin_amdgcn_mfma_f32_16x16x32_bf16(a[st][kk], ba[kk], acc, 0, 0, 0);
#pragma unroll
        for (int r = 0; r < 4; ++r) {
          int rrel = st * 16 + ks * 4 + r;
          size_t p = (size_t)(row0 + rrel) * 128 + o;
          float nx = 0.f;
          if (rrel < wrows) {
            nx = acc[r] * alpha + xio[p] * beta;
            xio[p] = nx;
          }
          qsh[t][rrel][o] = b16(nx);
        }
      }
    }
  }
  __syncthreads();

  // ---- Phase B: A-frags from LDS (both waves), then overwrite with q ----
  bf16x8 a[2][4];
#pragma unroll
  for (int st = 0; st < 2; ++st)
#pragma unroll
    for (int kk = 0; kk < 4; ++kk)
      a[st][kk] = ld_frag(&qsh[t][st * 16 + r16][ks * 8 + kk * 32]);
  __syncthreads();

  const unsigned short* WK = WT + (size_t)(0 * 3 + ty) * 16384;
  const unsigned short* WQ = WT + (size_t)(1 * 3 + ty) * 16384;
  const unsigned short* WV = WT + (size_t)(2 * 3 + ty) * 16384;
#pragma unroll 1
  for (int ct = ch * 4; ct < ch * 4 + 4; ++ct) {
    int o = ct * 16 + r16;
    bf16x8 fbk[4], fbq[4], fbv[4];
#pragma unroll
    for (int kk = 0; kk < 4; ++kk) {
      fbk[kk] = ld_frag(WK + (size_t)o * 128 + ks * 8 + kk * 32);
      fbq[kk] = ld_frag(WQ + (size_t)o * 128 + ks * 8 + kk * 32);
      fbv[kk] = ld_frag(WV + (size_t)o * 128 + ks * 8 + kk * 32);
    }
#pragma unroll
    for (int st = 0; st < 2; ++st) {
      f32x4 ak = {0.f,0.f,0.f,0.f}, aq = {0.f,0.f,0.f,0.f}, av = {0.f,0.f,0.f,0.f};
#pragma unroll
      for (int kk = 0; kk < 4; ++kk) {
        ak = __builtin_amdgcn_mfma_f32_16x16x32_bf16(a[st][kk], fbk[kk], ak, 0, 0, 0);
        aq = __builtin_amdgcn_mfma_f32_16x16x32_bf16(a[st][kk], fbq[kk], aq, 0, 0, 0);
        av = __builtin_amdgcn_mfma_f32_16x16x32_bf16(a[st][kk], fbv[kk], av, 0, 0, 0);
      }
#pragma unroll
      for (int r = 0; r < 4; ++r) {
        int rrel = st * 16 + ks * 4 + r;
        float kn = __shfl_xor(ak[r], 1);
        float vn = __shfl_xor(av[r], 1);
        qsh[t][rrel][o] = b16(aq[r]);          // now holds q rows
        if (rrel < wrows && (l & 1) == 0) {
          size_t p = (size_t)(row0 + rrel);
          kvb[p * 64 + (o >> 1)] = make_uint2(bpack(ak[r], kn), bpack(av[r], vn));
        }
      }
    }
  }
  __syncthreads();

  // ---- qa phase: rows [ch*16, ch*16+16) ----
  int h = l >> 3, j = l & 7;
  float4 prh = ((const float4*)pri)[h];
  float prs[4] = { prh.x * 0.25f, prh.y * 0.25f, prh.z * 0.25f, prh.w * 0.25f };
  int nd0 = ch * 16;
  int lim = wrows - nd0; if (lim > 16) lim = 16;
  for (int i = 0; i < lim; ++i) {
    int nd = nd0 + i;
    unsigned u[8];
    *(uint4*)&u[0] = *(uint4*)&qsh[t][nd][h * 16 + 0];
    *(uint4*)&u[4] = *(uint4*)&qsh[t][nd][h * 16 + 8];
    float qf[16];
#pragma unroll
    for (int q2 = 0; q2 < 8; ++q2) { qf[2*q2] = blo(u[q2]); qf[2*q2+1] = bhi(u[q2]); }
    unsigned pk[4];
#pragma unroll
    for (int t4 = 0; t4 < 4; ++t4) {
      const float* Ar = rel_att + (((h * 4 + t4) * 16) + 2 * j) * 16;
      float ax = 0.f, ay = 0.f;
#pragma unroll
      for (int o = 0; o < 16; ++o) {
        ax += Ar[o] * qf[o];
        ay += Ar[16 + o] * qf[o];
      }
      pk[t4] = bpack(ax * prs[t4], ay * prs[t4]);
    }
    qab[(size_t)(row0 + nd) * 64 + l] = make_uint4(pk[0], pk[1], pk[2], pk[3]);
  }
}

// ---- final typed output projection + sigmoid-skip residual ---------------
__global__ __launch_bounds__(256) void k_out(const unsigned short* __restrict__ hbh,
                                             const unsigned short* __restrict__ WT,
                                             const float* __restrict__ skipv,
                                             float* __restrict__ xio) {
  int w = threadIdx.x >> 6, l = threadIdx.x & 63;
  int r16 = l & 15, ks = l >> 4;
  int t = w >> 1, ch = w & 1;
  int tile = blockIdx.x * 2 + t;
  int ty, base, wrows;
  seg_decode(tile, ty, base, wrows);
  int row0 = base;

  bf16x8 a[2][4];
#pragma unroll
  for (int st = 0; st < 2; ++st) {
    const unsigned short* hrow = hbh + (size_t)(row0 + st * 16 + r16) * 128 + ks * 8;
#pragma unroll
    for (int kk = 0; kk < 4; ++kk) a[st][kk] = ld_frag(hrow + kk * 32);
  }

  const unsigned short* WA = WT + (size_t)(3 * 3 + ty) * 16384;
  float alpha = 1.f / (1.f + __expf(-skipv[ty]));
  float beta = 1.f - alpha;

#pragma unroll 1
  for (int ct = ch * 4; ct < ch * 4 + 4; ++ct) {
    int o = ct * 16 + r16;
    bf16x8 ba[4];
#pragma unroll
    for (int kk = 0; kk < 4; ++kk)
      ba[kk] = ld_frag(WA + (size_t)o * 128 + ks * 8 + kk * 32);
#pragma unroll
    for (int st = 0; st < 2; ++st) {
      f32x4 acc = {0.f,0.f,0.f,0.f};
#pragma unroll
      for (int kk = 0; kk < 4; ++kk)
        acc = __builtin_amdgcn_mfma_f32_16x16x32_bf16(a[st][kk], ba[kk], acc, 0, 0, 0);
#pragma unroll
      for (int r = 0; r < 4; ++r) {
        int rrel = st * 16 + ks * 4 + r;
        if (rrel < wrows) {
          size_t p = (size_t)(row0 + rrel) * 128 + o;
          xio[p] = acc[r] * alpha + xio[p] * beta;
        }
      }
    }
  }
}

extern "C" void kernel_launch(void* const* d_in, const int* in_sizes, int n_in,
                              void* d_out, int out_size, void* d_ws, size_t ws_size,
                              hipStream_t stream) {
  const float* drug = (const float*)d_in[0];
  const float* dis  = (const float*)d_in[1];
  const float* prot = (const float*)d_in[2];
  const int* src    = (const int*)d_in[3];
  const int* dst    = (const int*)d_in[4];
  const int* etp    = (const int*)d_in[5];
  const float* Wk   = (const float*)d_in[6];
  const float* Wq   = (const float*)d_in[7];
  const float* Wv   = (const float*)d_in[8];
  const float* Wa   = (const float*)d_in[9];
  const float* rel_att = (const float*)d_in[10];
  const float* rel_msg = (const float*)d_in[11];
  const float* pri  = (const float*)d_in[12];
  const float* skip = (const float*)d_in[13];
  float* x = (float*)d_out;

  char* w = (char*)d_ws;
  uint2*          kvb = (uint2*)(w + 0);              // 25,600,000
  unsigned*       hbh = (unsigned*)(w + 25600000);    // 12,800,000
  uint4*          qab = (uint4*)(w + 38400000);       // 51,200,000
  unsigned short* xh  = (unsigned short*)(w + 89600000);  // 12,800,000
  unsigned short* WT  = (unsigned short*)(w + 102400000); //    393,216
  float*          AmT = (float*)(w + 102793216);      //     32,768
  int*            off = (int*)(w + 102825984);        //    200,004
  int*            est = (int*)(w + 103026048);        //  1,600,512 (padded by 128)
  // deg/cur alias hbh region (dead until first k_fused write)
  int*            deg = (int*)(w + 25600000);
  int*            cur = (int*)(w + 25800064);

  (void)hipMemsetAsync(deg, 0, N_NODE * sizeof(int), stream);
  k_setup<<<SB_TOTAL, 256, 0, stream>>>(drug, dis, prot, x, xh, dst, deg,
                                        Wk, Wq, Wv, Wa, WT, rel_msg, AmT);
  k_scan<<<1, 1024, 0, stream>>>(deg, off, cur);
  k_fill<<<(N_EDGE + 128 + 255) / 256, 256, 0, stream>>>(dst, src, etp, cur, est);

  // layer 0
  k_qkv<<<PBLOCKS2, 256, 0, stream>>>(xh, WT, rel_att, pri, kvb, qab);
  k_fused<<<FUSED_BLOCKS, 256, 0, stream>>>(kvb, qab, off, est, AmT, hbh);
  // layer-0 out + layer-1 qkv fused
  k_outqkv<<<PBLOCKS2, 256, 0, stream>>>((const unsigned short*)hbh, WT, skip,
                                         rel_att, pri, x, kvb, qab);
  // layer 1
  k_fused<<<FUSED_BLOCKS, 256, 0, stream>>>(kvb, qab, off, est, AmT, hbh);
  k_out<<<PBLOCKS2, 256, 0, stream>>>((const unsigned short*)hbh, WT, skip, x);
}

// Round 20
// 689.048 us; speedup vs baseline: 1.9029x; 1.9029x over previous
//
#include <hip/hip_runtime.h>

#define N_NODE 50000
#define N_EDGE 400000
#define INF    128

#define FUSED_BLOCKS 1536   // 6 blocks/CU x 4 waves = 24 waves/CU at VGPR<=85

// 32-row tiles within type segments (boundaries 10000/20000 are 16-aligned)
#define TILES0 313
#define TILES1 313
#define TILES2 938
#define PTILES 1564
#define PBLOCKS2 782        // 2 tiles/block, 2 waves per tile (ct-split)

// k_setup grid partition
#define SB_CONCAT 2048
#define SB_COUNT  1563
#define SB_TWT    768
#define SB_TRMSG  32
#define SB_TOTAL  (SB_CONCAT + SB_COUNT + SB_TWT + SB_TRMSG)

typedef __bf16 bf16x8 __attribute__((ext_vector_type(8)));
typedef float  f32x4  __attribute__((ext_vector_type(4)));

__device__ __forceinline__ void seg_decode(int b, int& ty, int& base, int& nrows) {
  if (b < TILES0)            { ty = 0; base = b * 32;                      nrows = 10000 - base; }
  else if (b < TILES0+TILES1){ ty = 1; base = 10000 + (b - TILES0) * 32;   nrows = 20000 - base; }
  else                       { ty = 2; base = 20000 + (b - TILES0-TILES1)*32; nrows = 50000 - base; }
  if (nrows > 32) nrows = 32;
}

__device__ __forceinline__ float blo(unsigned u) { return __uint_as_float(u << 16); }
__device__ __forceinline__ float bhi(unsigned u) { return __uint_as_float(u & 0xffff0000u); }
// pack two f32 -> bf16x2 (RNE), lo = even dim, hi = odd dim
__device__ __forceinline__ unsigned bpack(float lo, float hi) {
  unsigned a = __float_as_uint(lo), b = __float_as_uint(hi);
  a = (a + 0x7fffu + ((a >> 16) & 1u)) >> 16;
  b = (b + 0x7fffu + ((b >> 16) & 1u)) & 0xffff0000u;
  return a | b;
}
__device__ __forceinline__ unsigned short b16(float v) {
  unsigned u = __float_as_uint(v);
  return (unsigned short)((u + 0x7fffu + ((u >> 16) & 1u)) >> 16);
}
__device__ __forceinline__ bf16x8 ld_frag(const unsigned short* p) {
  uint4 u = *reinterpret_cast<const uint4*>(p);
  return __builtin_bit_cast(bf16x8, u);
}

// ---- merged setup: concat(x,xh) | deg count | WT transpose | AmT ---------
__global__ __launch_bounds__(256) void k_setup(const float* __restrict__ dr,
                                               const float* __restrict__ di,
                                               const float* __restrict__ pr,
                                               float* __restrict__ x,
                                               unsigned short* __restrict__ xh,
                                               const int* __restrict__ dst,
                                               int* __restrict__ deg,
                                               const float* __restrict__ Wk,
                                               const float* __restrict__ Wq,
                                               const float* __restrict__ Wv,
                                               const float* __restrict__ Wa,
                                               unsigned short* __restrict__ WT,
                                               const float* __restrict__ rm,
                                               float* __restrict__ AmT) {
  int b = blockIdx.x;
  if (b < SB_CONCAT) {
    for (int i = b * 256 + threadIdx.x; i < N_NODE * 32; i += SB_CONCAT * 256) {
      int row = i >> 5;
      float4 val;
      if (row < 10000)      val = ((const float4*)dr)[i];
      else if (row < 20000) val = ((const float4*)di)[i - 10000*32];
      else                  val = ((const float4*)pr)[i - 20000*32];
      ((float4*)x)[i] = val;
      ((uint2*)xh)[i] = make_uint2(bpack(val.x, val.y), bpack(val.z, val.w));
    }
  } else if (b < SB_CONCAT + SB_COUNT) {
    int e = (b - SB_CONCAT) * 256 + threadIdx.x;
    if (e < N_EDGE) atomicAdd(&deg[dst[e]], 1);
  } else if (b < SB_CONCAT + SB_COUNT + SB_TWT) {
    int idx = (b - SB_CONCAT - SB_COUNT) * 256 + threadIdx.x;
    if (idx < 196608) {
      int mt = idx >> 14;            // mat*3+ty
      int within = idx & 16383;
      int o = within >> 7, ii = within & 127;
      int mat = mt / 3, ty = mt % 3;
      const float* W = (mat == 0) ? Wk : (mat == 1) ? Wq : (mat == 2) ? Wv : Wa;
      WT[idx] = b16(W[ty * 16384 + ii * 128 + o]);
    }
  } else {
    int i = (b - SB_CONCAT - SB_COUNT - SB_TWT) * 256 + threadIdx.x;  // < 8192
    int di2 = i & 15, doo = (i >> 4) & 15, ty = (i >> 8) & 3, hh = i >> 10;
    AmT[i] = rm[((hh * 4 + ty) * 16 + di2) * 16 + doo];
  }
}

// ---- CSR scan ------------------------------------------------------------
__global__ __launch_bounds__(1024) void k_scan(const int* __restrict__ deg,
                                               int* __restrict__ off, int* __restrict__ cur) {
  __shared__ int part[1024];
  int t = threadIdx.x;
  int c0 = t * 49;
  int c1 = c0 + 49; if (c1 > N_NODE) c1 = N_NODE;
  int s = 0;
  for (int i = c0; i < c1; ++i) s += deg[i];
  part[t] = s;
  __syncthreads();
  for (int ofs = 1; ofs < 1024; ofs <<= 1) {
    int v = (t >= ofs) ? part[t - ofs] : 0;
    __syncthreads();
    part[t] += v;
    __syncthreads();
  }
  int run = (t == 0) ? 0 : part[t - 1];
  for (int i = c0; i < c1; ++i) { off[i] = run; cur[i] = run; run += deg[i]; }
  if (t == 1023) off[N_NODE] = part[1023];
}

// writes combined edge record est[p] = (src<<2) | etype; pads est tail with 0
__global__ __launch_bounds__(256) void k_fill(const int* __restrict__ dst,
                                              const int* __restrict__ src,
                                              const int* __restrict__ etp,
                                              int* __restrict__ cur, int* __restrict__ est) {
  int e = blockIdx.x * 256 + threadIdx.x;
  if (e < N_EDGE) {
    int p = atomicAdd(&cur[dst[e]], 1);
    est[p] = (src[e] << 2) | etp[e];
  } else if (e < N_EDGE + 64) {
    est[e] = 0;
  }
}

// ---- typed K/Q/V projection via MFMA + fused qa precompute ---------------
// 2 waves per 32-row tile; wave owns 4 of 8 ct-columns.
__global__ __launch_bounds__(256) void k_qkv(const unsigned short* __restrict__ xh,
                                             const unsigned short* __restrict__ WT,
                                             const float* __restrict__ rel_att,
                                             const float* __restrict__ pri,
                                             uint2* __restrict__ kvb,
                                             uint4* __restrict__ qab) {
  __shared__ unsigned short qsh[2][32][136];   // bf16 q rows per tile, 17.4 KB
  int w = threadIdx.x >> 6, l = threadIdx.x & 63;
  int r16 = l & 15, ks = l >> 4;
  int t = w >> 1, ch = w & 1;
  int tile = blockIdx.x * 2 + t;
  int ty, base, wrows;
  seg_decode(tile, ty, base, wrows);
  int row0 = base;

  bf16x8 a[2][4];
#pragma unroll
  for (int st = 0; st < 2; ++st) {
    const unsigned short* xrow = xh + (size_t)(row0 + st * 16 + r16) * 128 + ks * 8;
#pragma unroll
    for (int kk = 0; kk < 4; ++kk) a[st][kk] = ld_frag(xrow + kk * 32);
  }

  const unsigned short* WK = WT + (size_t)(0 * 3 + ty) * 16384;
  const unsigned short* WQ = WT + (size_t)(1 * 3 + ty) * 16384;
  const unsigned short* WV = WT + (size_t)(2 * 3 + ty) * 16384;

#pragma unroll 1
  for (int ct = ch * 4; ct < ch * 4 + 4; ++ct) {
    int o = ct * 16 + r16;
    bf16x8 fbk[4], fbq[4], fbv[4];
#pragma unroll
    for (int kk = 0; kk < 4; ++kk) {
      fbk[kk] = ld_frag(WK + (size_t)o * 128 + ks * 8 + kk * 32);
      fbq[kk] = ld_frag(WQ + (size_t)o * 128 + ks * 8 + kk * 32);
      fbv[kk] = ld_frag(WV + (size_t)o * 128 + ks * 8 + kk * 32);
    }
#pragma unroll
    for (int st = 0; st < 2; ++st) {
      f32x4 ak = {0.f,0.f,0.f,0.f}, aq = {0.f,0.f,0.f,0.f}, av = {0.f,0.f,0.f,0.f};
#pragma unroll
      for (int kk = 0; kk < 4; ++kk) {
        ak = __builtin_amdgcn_mfma_f32_16x16x32_bf16(a[st][kk], fbk[kk], ak, 0, 0, 0);
        aq = __builtin_amdgcn_mfma_f32_16x16x32_bf16(a[st][kk], fbq[kk], aq, 0, 0, 0);
        av = __builtin_amdgcn_mfma_f32_16x16x32_bf16(a[st][kk], fbv[kk], av, 0, 0, 0);
      }
#pragma unroll
      for (int r = 0; r < 4; ++r) {
        int rrel = st * 16 + ks * 4 + r;       // < 32 always
        float kn = __shfl_xor(ak[r], 1);
        float vn = __shfl_xor(av[r], 1);
        qsh[t][rrel][o] = b16(aq[r]);
        if (rrel < wrows && (l & 1) == 0) {
          size_t p = (size_t)(row0 + rrel);
          kvb[p * 64 + (o >> 1)] = make_uint2(bpack(ak[r], kn), bpack(av[r], vn));
        }
      }
    }
  }
  __syncthreads();

  // ---- qa phase: this wave handles rows [ch*16, ch*16+16) of its tile ----
  int h = l >> 3, j = l & 7;
  float4 prh = ((const float4*)pri)[h];
  float prs[4] = { prh.x * 0.25f, prh.y * 0.25f, prh.z * 0.25f, prh.w * 0.25f };
  int nd0 = ch * 16;
  int lim = wrows - nd0; if (lim > 16) lim = 16;
  for (int i = 0; i < lim; ++i) {
    int nd = nd0 + i;
    unsigned u[8];
    *(uint4*)&u[0] = *(uint4*)&qsh[t][nd][h * 16 + 0];
    *(uint4*)&u[4] = *(uint4*)&qsh[t][nd][h * 16 + 8];
    float qf[16];
#pragma unroll
    for (int q2 = 0; q2 < 8; ++q2) { qf[2*q2] = blo(u[q2]); qf[2*q2+1] = bhi(u[q2]); }
    unsigned pk[4];
#pragma unroll
    for (int t4 = 0; t4 < 4; ++t4) {
      const float* Ar = rel_att + (((h * 4 + t4) * 16) + 2 * j) * 16;
      float ax = 0.f, ay = 0.f;
#pragma unroll
      for (int o = 0; o < 16; ++o) {
        ax += Ar[o] * qf[o];
        ay += Ar[16 + o] * qf[o];
      }
      pk[t4] = bpack(ax * prs[t4], ay * prs[t4]);
    }
    qab[(size_t)(row0 + nd) * 64 + l] = make_uint4(pk[0], pk[1], pk[2], pk[3]);
  }
}

// ---- fused attention: logits + edge-softmax + aggregation ---------------
// PERSISTENT: FUSED_BLOCKS x 4 waves, 1 wave per node (grid-stride).
// R18-proven operating point: 1 node/wave, 2-deep prefetch, waves_per_eu(3,6)
// (VGPR 84, ~24 waves/CU, 168us). R19's 2-node/wave variant spilled (live
// state ~110 regs > 85 budget) -> reverted.
__global__ __launch_bounds__(256)
__attribute__((amdgpu_waves_per_eu(3, 6)))
void k_fused(const uint2* __restrict__ kvb,
             const uint4* __restrict__ qab,
             const int* __restrict__ off,
             const int* __restrict__ est,
             const float* __restrict__ AmT,
             unsigned* __restrict__ hbh) {
  __shared__ float accs[4][4][128];
  int w = threadIdx.x >> 6, l = threadIdx.x & 63;
  int h = l >> 3, j = l & 7;

  for (int n = blockIdx.x * 4 + w; n < N_NODE; n += FUSED_BLOCKS * 4) {
    int o0 = off[n], o1 = off[n + 1];

    uint4 qu = qab[(size_t)n * 64 + l];
    float2 qa0 = make_float2(blo(qu.x), bhi(qu.x));
    float2 qa1 = make_float2(blo(qu.y), bhi(qu.y));
    float2 qa2 = make_float2(blo(qu.z), bhi(qu.z));
    float2 qa3 = make_float2(blo(qu.w), bhi(qu.w));

    float ssum = 0.f;
    float2 z = make_float2(0.f, 0.f);
    float2 at0 = z, at1 = z, at2 = z, at3 = z;

#define PROC(KV, TY, VALID) { \
    int ty = (TY) & 3; \
    float kx = blo((KV).x), ky = bhi((KV).x); \
    float2 qat = (ty==0)?qa0:(ty==1)?qa1:(ty==2)?qa2:qa3; \
    float part = kx*qat.x + ky*qat.y; \
    part += __shfl_xor(part, 1); \
    part += __shfl_xor(part, 2); \
    part += __shfl_xor(part, 4); \
    float wgt = (VALID) ? __expf(part) : 0.f; \
    ssum += wgt; \
    float vx = blo((KV).y), vy = bhi((KV).y); \
    float w0=(ty==0)?wgt:0.f, w1=(ty==1)?wgt:0.f, w2=(ty==2)?wgt:0.f, w3=(ty==3)?wgt:0.f; \
    at0.x += w0*vx; at0.y += w0*vy; \
    at1.x += w1*vx; at1.y += w1*vy; \
    at2.x += w2*vx; at2.y += w2*vy; \
    at3.x += w3*vx; at3.y += w3*vy; }

    for (int b0 = o0; b0 < o1; b0 += 64) {
      int cnt = o1 - b0; if (cnt > 64) cnt = 64;
      int stv = est[b0 + (l < cnt ? l : cnt - 1)];   // clamped: 1 line for deg<=32
      int t0 = __shfl(stv, 0);
      int t1 = __shfl(stv, 1 < cnt ? 1 : 0);
      uint2 kv0 = kvb[(size_t)(t0 >> 2) * 64 + l];
      uint2 kv1 = kvb[(size_t)(t1 >> 2) * 64 + l];
      for (int i = 0; i < cnt; i += 2) {
        bool more = (i + 2) < cnt;        // wave-uniform
        int n0 = 0, n1 = 0; uint2 kn0, kn1;
        if (more) {
          n0 = __shfl(stv, i + 2);
          n1 = __shfl(stv, (i + 3) < cnt ? (i + 3) : (i + 2));
          kn0 = kvb[(size_t)(n0 >> 2) * 64 + l];
          kn1 = kvb[(size_t)(n1 >> 2) * 64 + l];
        }
        PROC(kv0, t0, true)
        PROC(kv1, t1, (i + 1) < cnt)
        if (more) { t0 = n0; t1 = n1; kv0 = kn0; kv1 = kn1; }
      }
    }
#undef PROC

    float inv = (ssum > 0.f) ? 1.f / ssum : 0.f;
    at0.x *= inv; at0.y *= inv;
    at1.x *= inv; at1.y *= inv;
    at2.x *= inv; at2.y *= inv;
    at3.x *= inv; at3.y *= inv;

    ((float2*)&accs[w][0][0])[l] = at0;
    ((float2*)&accs[w][1][0])[l] = at1;
    ((float2*)&accs[w][2][0])[l] = at2;
    ((float2*)&accs[w][3][0])[l] = at3;

    float ox = 0.f, oy = 0.f;
#pragma unroll
    for (int ty = 0; ty < 4; ++ty) {
      const float4* AmR = (const float4*)(AmT + ((h * 4 + ty) * 16) * 16);
#pragma unroll
      for (int d4 = 0; d4 < 4; ++d4) {
        float4 ac = *((float4*)&accs[w][ty][h * 16 + d4 * 4]);
        float4 m0 = AmR[(2 * j) * 4 + d4];
        float4 m1 = AmR[(2 * j + 1) * 4 + d4];
        ox += m0.x * ac.x + m0.y * ac.y + m0.z * ac.z + m0.w * ac.w;
        oy += m1.x * ac.x + m1.y * ac.y + m1.z * ac.z + m1.w * ac.w;
      }
    }
    hbh[(size_t)n * 64 + l] = bpack(ox, oy);   // dims (2l, 2l+1)
  }
}

// ---- fused: output proj (layer L) + K/Q/V proj (layer L+1) ---------------
__global__ __launch_bounds__(256) void k_outqkv(const unsigned short* __restrict__ hbh,
                                                const unsigned short* __restrict__ WT,
                                                const float* __restrict__ skipv,
                                                const float* __restrict__ rel_att,
                                                const float* __restrict__ pri,
                                                float* __restrict__ xio,
                                                uint2* __restrict__ kvb,
                                                uint4* __restrict__ qab) {
  __shared__ unsigned short qsh[2][32][136];   // 17.4 KB
  int w = threadIdx.x >> 6, l = threadIdx.x & 63;
  int r16 = l & 15, ks = l >> 4;
  int t = w >> 1, ch = w & 1;
  int tile = blockIdx.x * 2 + t;
  int ty, base, wrows;
  seg_decode(tile, ty, base, wrows);
  int row0 = base;

  // ---- Phase A: output projection + sigmoid-skip residual (4 cts) ----
  {
    bf16x8 a[2][4];
#pragma unroll
    for (int st = 0; st < 2; ++st) {
      const unsigned short* hrow = hbh + (size_t)(row0 + st * 16 + r16) * 128 + ks * 8;
#pragma unroll
      for (int kk = 0; kk < 4; ++kk) a[st][kk] = ld_frag(hrow + kk * 32);
    }
    const unsigned short* WA = WT + (size_t)(3 * 3 + ty) * 16384;
    float alpha = 1.f / (1.f + __expf(-skipv[ty]));
    float beta = 1.f - alpha;
#pragma unroll 1
    for (int ct = ch * 4; ct < ch * 4 + 4; ++ct) {
      int o = ct * 16 + r16;
      bf16x8 ba[4];
#pragma unroll
      for (int kk = 0; kk < 4; ++kk)
        ba[kk] = ld_frag(WA + (size_t)o * 128 + ks * 8 + kk * 32);
#pragma unroll
      for (int st = 0; st < 2; ++st) {
        f32x4 acc = {0.f,0.f,0.f,0.f};
#pragma unroll
        for (int kk = 0; kk < 4; ++kk)
          acc = __builtin_amdgcn_mfma_f32_16x16x32_bf16(a[st][kk], ba[kk], acc, 0, 0, 0);
#pragma unroll
        for (int r = 0; r < 4; ++r) {
          int rrel = st * 16 + ks * 4 + r;
          size_t p = (size_t)(row0 + rrel) * 128 + o;
          float nx = 0.f;
          if (rrel < wrows) {
            nx = acc[r] * alpha + xio[p] * beta;
            xio[p] = nx;
          }
          qsh[t][rrel][o] = b16(nx);
        }
      }
    }
  }
  __syncthreads();

  // ---- Phase B: A-frags from LDS (both waves), then overwrite with q ----
  bf16x8 a[2][4];
#pragma unroll
  for (int st = 0; st < 2; ++st)
#pragma unroll
    for (int kk = 0; kk < 4; ++kk)
      a[st][kk] = ld_frag(&qsh[t][st * 16 + r16][ks * 8 + kk * 32]);
  __syncthreads();

  const unsigned short* WK = WT + (size_t)(0 * 3 + ty) * 16384;
  const unsigned short* WQ = WT + (size_t)(1 * 3 + ty) * 16384;
  const unsigned short* WV = WT + (size_t)(2 * 3 + ty) * 16384;
#pragma unroll 1
  for (int ct = ch * 4; ct < ch * 4 + 4; ++ct) {
    int o = ct * 16 + r16;
    bf16x8 fbk[4], fbq[4], fbv[4];
#pragma unroll
    for (int kk = 0; kk < 4; ++kk) {
      fbk[kk] = ld_frag(WK + (size_t)o * 128 + ks * 8 + kk * 32);
      fbq[kk] = ld_frag(WQ + (size_t)o * 128 + ks * 8 + kk * 32);
      fbv[kk] = ld_frag(WV + (size_t)o * 128 + ks * 8 + kk * 32);
    }
#pragma unroll
    for (int st = 0; st < 2; ++st) {
      f32x4 ak = {0.f,0.f,0.f,0.f}, aq = {0.f,0.f,0.f,0.f}, av = {0.f,0.f,0.f,0.f};
#pragma unroll
      for (int kk = 0; kk < 4; ++kk) {
        ak = __builtin_amdgcn_mfma_f32_16x16x32_bf16(a[st][kk], fbk[kk], ak, 0, 0, 0);
        aq = __builtin_amdgcn_mfma_f32_16x16x32_bf16(a[st][kk], fbq[kk], aq, 0, 0, 0);
        av = __builtin_amdgcn_mfma_f32_16x16x32_bf16(a[st][kk], fbv[kk], av, 0, 0, 0);
      }
#pragma unroll
      for (int r = 0; r < 4; ++r) {
        int rrel = st * 16 + ks * 4 + r;
        float kn = __shfl_xor(ak[r], 1);
        float vn = __shfl_xor(av[r], 1);
        qsh[t][rrel][o] = b16(aq[r]);          // now holds q rows
        if (rrel < wrows && (l & 1) == 0) {
          size_t p = (size_t)(row0 + rrel);
          kvb[p * 64 + (o >> 1)] = make_uint2(bpack(ak[r], kn), bpack(av[r], vn));
        }
      }
    }
  }
  __syncthreads();

  // ---- qa phase: rows [ch*16, ch*16+16) ----
  int h = l >> 3, j = l & 7;
  float4 prh = ((const float4*)pri)[h];
  float prs[4] = { prh.x * 0.25f, prh.y * 0.25f, prh.z * 0.25f, prh.w * 0.25f };
  int nd0 = ch * 16;
  int lim = wrows - nd0; if (lim > 16) lim = 16;
  for (int i = 0; i < lim; ++i) {
    int nd = nd0 + i;
    unsigned u[8];
    *(uint4*)&u[0] = *(uint4*)&qsh[t][nd][h * 16 + 0];
    *(uint4*)&u[4] = *(uint4*)&qsh[t][nd][h * 16 + 8];
    float qf[16];
#pragma unroll
    for (int q2 = 0; q2 < 8; ++q2) { qf[2*q2] = blo(u[q2]); qf[2*q2+1] = bhi(u[q2]); }
    unsigned pk[4];
#pragma unroll
    for (int t4 = 0; t4 < 4; ++t4) {
      const float* Ar = rel_att + (((h * 4 + t4) * 16) + 2 * j) * 16;
      float ax = 0.f, ay = 0.f;
#pragma unroll
      for (int o = 0; o < 16; ++o) {
        ax += Ar[o] * qf[o];
        ay += Ar[16 + o] * qf[o];
      }
      pk[t4] = bpack(ax * prs[t4], ay * prs[t4]);
    }
    qab[(size_t)(row0 + nd) * 64 + l] = make_uint4(pk[0], pk[1], pk[2], pk[3]);
  }
}

// ---- final typed output projection + sigmoid-skip residual ---------------
__global__ __launch_bounds__(256) void k_out(const unsigned short* __restrict__ hbh,
                                             const unsigned short* __restrict__ WT,
                                             const float* __restrict__ skipv,
                                             float* __restrict__ xio) {
  int w = threadIdx.x >> 6, l = threadIdx.x & 63;
  int r16 = l & 15, ks = l >> 4;
  int t = w >> 1, ch = w & 1;
  int tile = blockIdx.x * 2 + t;
  int ty, base, wrows;
  seg_decode(tile, ty, base, wrows);
  int row0 = base;

  bf16x8 a[2][4];
#pragma unroll
  for (int st = 0; st < 2; ++st) {
    const unsigned short* hrow = hbh + (size_t)(row0 + st * 16 + r16) * 128 + ks * 8;
#pragma unroll
    for (int kk = 0; kk < 4; ++kk) a[st][kk] = ld_frag(hrow + kk * 32);
  }

  const unsigned short* WA = WT + (size_t)(3 * 3 + ty) * 16384;
  float alpha = 1.f / (1.f + __expf(-skipv[ty]));
  float beta = 1.f - alpha;

#pragma unroll 1
  for (int ct = ch * 4; ct < ch * 4 + 4; ++ct) {
    int o = ct * 16 + r16;
    bf16x8 ba[4];
#pragma unroll
    for (int kk = 0; kk < 4; ++kk)
      ba[kk] = ld_frag(WA + (size_t)o * 128 + ks * 8 + kk * 32);
#pragma unroll
    for (int st = 0; st < 2; ++st) {
      f32x4 acc = {0.f,0.f,0.f,0.f};
#pragma unroll
      for (int kk = 0; kk < 4; ++kk)
        acc = __builtin_amdgcn_mfma_f32_16x16x32_bf16(a[st][kk], ba[kk], acc, 0, 0, 0);
#pragma unroll
      for (int r = 0; r < 4; ++r) {
        int rrel = st * 16 + ks * 4 + r;
        if (rrel < wrows) {
          size_t p = (size_t)(row0 + rrel) * 128 + o;
          xio[p] = acc[r] * alpha + xio[p] * beta;
        }
      }
    }
  }
}

extern "C" void kernel_launch(void* const* d_in, const int* in_sizes, int n_in,
                              void* d_out, int out_size, void* d_ws, size_t ws_size,
                              hipStream_t stream) {
  const float* drug = (const float*)d_in[0];
  const float* dis  = (const float*)d_in[1];
  const float* prot = (const float*)d_in[2];
  const int* src    = (const int*)d_in[3];
  const int* dst    = (const int*)d_in[4];
  const int* etp    = (const int*)d_in[5];
  const float* Wk   = (const float*)d_in[6];
  const float* Wq   = (const float*)d_in[7];
  const float* Wv   = (const float*)d_in[8];
  const float* Wa   = (const float*)d_in[9];
  const float* rel_att = (const float*)d_in[10];
  const float* rel_msg = (const float*)d_in[11];
  const float* pri  = (const float*)d_in[12];
  const float* skip = (const float*)d_in[13];
  float* x = (float*)d_out;

  char* w = (char*)d_ws;
  uint2*          kvb = (uint2*)(w + 0);              // 25,600,000
  unsigned*       hbh = (unsigned*)(w + 25600000);    // 12,800,000
  uint4*          qab = (uint4*)(w + 38400000);       // 51,200,000
  unsigned short* xh  = (unsigned short*)(w + 89600000);  // 12,800,000
  unsigned short* WT  = (unsigned short*)(w + 102400000); //    393,216
  float*          AmT = (float*)(w + 102793216);      //     32,768
  int*            off = (int*)(w + 102825984);        //    200,004
  int*            est = (int*)(w + 103026048);        //  1,600,256 (padded by 64)
  // deg/cur alias hbh region (dead until first k_fused write)
  int*            deg = (int*)(w + 25600000);
  int*            cur = (int*)(w + 25800064);

  (void)hipMemsetAsync(deg, 0, N_NODE * sizeof(int), stream);
  k_setup<<<SB_TOTAL, 256, 0, stream>>>(drug, dis, prot, x, xh, dst, deg,
                                        Wk, Wq, Wv, Wa, WT, rel_msg, AmT);
  k_scan<<<1, 1024, 0, stream>>>(deg, off, cur);
  k_fill<<<(N_EDGE + 64 + 255) / 256, 256, 0, stream>>>(dst, src, etp, cur, est);

  // layer 0
  k_qkv<<<PBLOCKS2, 256, 0, stream>>>(xh, WT, rel_att, pri, kvb, qab);
  k_fused<<<FUSED_BLOCKS, 256, 0, stream>>>(kvb, qab, off, est, AmT, hbh);
  // layer-0 out + layer-1 qkv fused
  k_outqkv<<<PBLOCKS2, 256, 0, stream>>>((const unsigned short*)hbh, WT, skip,
                                         rel_att, pri, x, kvb, qab);
  // layer 1
  k_fused<<<FUSED_BLOCKS, 256, 0, stream>>>(kvb, qab, off, est, AmT, hbh);
  k_out<<<PBLOCKS2, 256, 0, stream>>>((const unsigned short*)hbh, WT, skip, x);
}